// Round 8
// baseline (443.967 us; speedup 1.0000x reference)
//
#include <hip/hip_runtime.h>

#define N_NODES 50000
#define N_RELSR 20
#define R_TOT   41          // 2*N_RELSR + 1
#define N_EDGES 500000
#define EMB     16
#define NCLS    16
#define NB      40
#define E_TOT   (2 * N_EDGES + N_NODES)   // 1,050,000
#define NE_COL  (N_NODES * EMB)           // 800,000
#define NBLK_N  ((N_NODES + 255) / 256)   // 196

// f32 -> bf16 round-to-nearest-even (manual, no header dependency)
__device__ __forceinline__ unsigned short f2bf(float f) {
    unsigned u = __float_as_uint(f);
    u += 0x7FFFu + ((u >> 16) & 1u);
    return (unsigned short)(u >> 16);
}

// decode enriched edge i -> (s, o, r)
__device__ __forceinline__ void edge_decode(int i, const int* __restrict__ src,
                                            const int* __restrict__ dst,
                                            const int* __restrict__ rel,
                                            int& s, int& o, int& r) {
    if (i < N_EDGES) {
        s = src[i]; o = dst[i]; r = rel[i];
    } else if (i < 2 * N_EDGES) {
        int j = i - N_EDGES;
        s = dst[j]; o = src[j]; r = rel[j] + N_RELSR;
    } else {
        int n = i - 2 * N_EDGES;
        s = n; o = n; r = 2 * N_RELSR;
    }
}

// cnt2[idx] = { count, local r-prefix within node s }

// ---- K1: segment counts; also record each edge's rank within its segment ---
__global__ void k_count(const int* __restrict__ src, const int* __restrict__ dst,
                        const int* __restrict__ rel, int2* __restrict__ cnt2,
                        int* __restrict__ rank) {
    int i = blockIdx.x * blockDim.x + threadIdx.x;
    if (i >= E_TOT) return;
    int s, o, r;
    edge_decode(i, src, dst, rel, s, o, r);
    rank[i] = atomicAdd(&cnt2[r * N_NODES + s].x, 1);
}

// ---- K2a: deg[s] = sum_r cnt[r,s]; local r-prefix into .y; per-block sums ---
__global__ void k_degA(int2* __restrict__ cnt2, int* __restrict__ deg,
                       int* __restrict__ bsum) {
    __shared__ int red[256];
    int t = threadIdx.x;
    int s = blockIdx.x * 256 + t;
    int run = 0;
    if (s < N_NODES) {
        for (int r = 0; r < R_TOT; r++) {
            int idx = r * N_NODES + s;
            int2 val = cnt2[idx];
            val.y = run;              // local exclusive prefix over r
            cnt2[idx] = val;
            run += val.x;
        }
        deg[s] = run;
    }
    red[t] = run;
    __syncthreads();
    for (int st = 128; st > 0; st >>= 1) {
        if (t < st) red[t] += red[t + st];
        __syncthreads();
    }
    if (t == 0) bsum[blockIdx.x] = red[0];
}

// ---- K2b: exclusive scan of 196 block sums (single tiny block) --------------
__global__ void k_degB(int* __restrict__ bsum) {
    __shared__ int sh[256];
    int t = threadIdx.x;
    int v = (t < NBLK_N) ? bsum[t] : 0;
    sh[t] = v;
    __syncthreads();
    for (int d = 1; d < 256; d <<= 1) {
        int x = (t >= d) ? sh[t - d] : 0;
        __syncthreads();
        sh[t] += x;
        __syncthreads();
    }
    if (t < NBLK_N) bsum[t] = sh[t] - v;   // exclusive
}

// ---- K2c: block-local scan of deg -> off (global CSR offsets) ---------------
__global__ void k_degC(const int* __restrict__ deg, const int* __restrict__ bsum,
                       int* __restrict__ off) {
    __shared__ int sh[256];
    int t = threadIdx.x;
    int s = blockIdx.x * 256 + t;
    int d = (s < N_NODES) ? deg[s] : 0;
    sh[t] = d;
    __syncthreads();
    for (int dd = 1; dd < 256; dd <<= 1) {
        int x = (t >= dd) ? sh[t - dd] : 0;
        __syncthreads();
        sh[t] += x;
        __syncthreads();
    }
    int excl = sh[t] - d + bsum[blockIdx.x];
    if (s < N_NODES) off[s] = excl;
    if (s == 0) off[N_NODES] = E_TOT;
}

// ---- K3: fill CSR records {(r<<16)|o, v} sorted by (s, r); no atomics -------
__global__ void k_fill(const int* __restrict__ src, const int* __restrict__ dst,
                       const int* __restrict__ rel, const int2* __restrict__ cnt2,
                       const int* __restrict__ rank, const int* __restrict__ off,
                       int2* __restrict__ recs) {
    int i = blockIdx.x * blockDim.x + threadIdx.x;
    if (i >= E_TOT) return;
    int s, o, r;
    edge_decode(i, src, dst, rel, s, o, r);
    int2 cr = cnt2[r * N_NODES + s];
    float v = 1.0f / (float)cr.x;
    recs[off[s] + cr.y + rank[i]] = make_int2((r << 16) | o, __float_as_int(v));
}

// ---- K4: w1[r,n,e] = sum_b comps1[r,b] * bases1[b,n,e]  -> bf16 -------------
// LDS-staged, wave-partitioned r. Block = 8 waves, 64 float4-columns.
// bases1 read from HBM exactly once; re-reads come from the LDS tile.
// Wave w owns r in [5w, 5w+5) (wave 7 gets 6) -> float4 acc[6] = 24 VGPR only.
#define W1_COLS 64
__global__ void __launch_bounds__(512, 1)
k_w1(const float* __restrict__ comps1, const float* __restrict__ bases1,
     uint2* __restrict__ w1p2) {
    __shared__ float4 tile[NB][W1_COLS];   // 40,960 B
    __shared__ float  c1s[R_TOT * NB];     //  6,560 B
    int tid = threadIdx.x;
    for (int q = tid; q < R_TOT * NB; q += 512) c1s[q] = comps1[q];
    int j4base = blockIdx.x * W1_COLS;
    const float4* b4 = (const float4*)bases1;
    for (int q = tid; q < NB * W1_COLS; q += 512) {
        int b = q >> 6, jc = q & 63;
        tile[b][jc] = b4[(size_t)b * (NE_COL / 4) + j4base + jc];
    }
    __syncthreads();
    int wave = tid >> 6, lane = tid & 63;
    int r0 = wave * 5;
    int nr = (wave == 7) ? 6 : 5;
    float4 acc[6];
#pragma unroll
    for (int k = 0; k < 6; k++) { acc[k].x = 0.f; acc[k].y = 0.f; acc[k].z = 0.f; acc[k].w = 0.f; }
    for (int b = 0; b < NB; b++) {
        float4 bb = tile[b][lane];
#pragma unroll
        for (int k = 0; k < 6; k++) {          // k=5 extra compute discarded for waves 0-6
            float cc = c1s[(r0 + k) * NB + b]; // r0+5 <= 40 always: index safe
            acc[k].x = fmaf(cc, bb.x, acc[k].x);
            acc[k].y = fmaf(cc, bb.y, acc[k].y);
            acc[k].z = fmaf(cc, bb.z, acc[k].z);
            acc[k].w = fmaf(cc, bb.w, acc[k].w);
        }
    }
#pragma unroll
    for (int k = 0; k < 6; k++) {
        if (k < nr) {
            uint2 pk;
            pk.x = ((unsigned)f2bf(acc[k].y) << 16) | (unsigned)f2bf(acc[k].x);
            pk.y = ((unsigned)f2bf(acc[k].w) << 16) | (unsigned)f2bf(acc[k].z);
            w1p2[(size_t)(r0 + k) * (NE_COL / 4) + j4base + lane] = pk;
        }
    }
}

// ---- K5: w2t[r,c,e] = sum_b comps2[r,b] * bases2[b,e,c]  (transposed) -------
__global__ void k_w2(const float* __restrict__ comps2, const float* __restrict__ bases2,
                     float* __restrict__ w2t) {
    int r = blockIdx.x;        // 41 blocks
    int t = threadIdx.x;       // 256 = NCLS*EMB, t = c*16+e
    int c = t >> 4, e = t & 15;
    float acc = 0.f;
#pragma unroll 8
    for (int b = 0; b < NB; b++) acc += comps2[r * NB + b] * bases2[b * (EMB * NCLS) + e * NCLS + c];
    w2t[r * (EMB * NCLS) + t] = acc;
}

// ---- K6: layer-1 gather, 8 lanes/edge: each lane loads one bf16x2 (uint) ----
// and produces h[s, 2*e2] and h[s, 2*e2+1]. Same per-element math order.
__global__ void k_l1_gather(const int* __restrict__ off, const int2* __restrict__ recs,
                            const unsigned* __restrict__ w1p,
                            const float* __restrict__ bias1, float* __restrict__ h) {
    int t = blockIdx.x * blockDim.x + threadIdx.x;     // N_NODES*8
    if (t >= N_NODES * 8) return;
    int s = t >> 3, e2 = t & 7;
    int beg = off[s], end = off[s + 1];
    float ax = 0.f, ay = 0.f;
    int j = beg;
    for (; j + 3 < end; j += 4) {
        int2 r0 = recs[j], r1 = recs[j + 1], r2 = recs[j + 2], r3 = recs[j + 3];
        unsigned p0 = w1p[(size_t)(r0.x >> 16) * (NE_COL / 2) + (r0.x & 0xFFFF) * 8 + e2];
        unsigned p1 = w1p[(size_t)(r1.x >> 16) * (NE_COL / 2) + (r1.x & 0xFFFF) * 8 + e2];
        unsigned p2 = w1p[(size_t)(r2.x >> 16) * (NE_COL / 2) + (r2.x & 0xFFFF) * 8 + e2];
        unsigned p3 = w1p[(size_t)(r3.x >> 16) * (NE_COL / 2) + (r3.x & 0xFFFF) * 8 + e2];
        float v0 = __int_as_float(r0.y), v1 = __int_as_float(r1.y);
        float v2 = __int_as_float(r2.y), v3 = __int_as_float(r3.y);
        ax = fmaf(v0, __uint_as_float(p0 << 16), ax);
        ay = fmaf(v0, __uint_as_float(p0 & 0xFFFF0000u), ay);
        ax = fmaf(v1, __uint_as_float(p1 << 16), ax);
        ay = fmaf(v1, __uint_as_float(p1 & 0xFFFF0000u), ay);
        ax = fmaf(v2, __uint_as_float(p2 << 16), ax);
        ay = fmaf(v2, __uint_as_float(p2 & 0xFFFF0000u), ay);
        ax = fmaf(v3, __uint_as_float(p3 << 16), ax);
        ay = fmaf(v3, __uint_as_float(p3 & 0xFFFF0000u), ay);
    }
    for (; j < end; j++) {
        int2 rc = recs[j];
        unsigned p = w1p[(size_t)(rc.x >> 16) * (NE_COL / 2) + (rc.x & 0xFFFF) * 8 + e2];
        float v = __int_as_float(rc.y);
        ax = fmaf(v, __uint_as_float(p << 16), ax);
        ay = fmaf(v, __uint_as_float(p & 0xFFFF0000u), ay);
    }
    float2 res;
    res.x = fmaxf(ax + bias1[2 * e2], 0.f);
    res.y = fmaxf(ay + bias1[2 * e2 + 1], 0.f);
    ((float2*)h)[t] = res;
}

// ---- K6-alt (fallback if ws too small for w1): on-the-fly basis contraction -
__global__ void k_l1_gather_fly(const int* __restrict__ off, const int2* __restrict__ recs,
                                const float* __restrict__ comps1,
                                const float* __restrict__ bases1,
                                const float* __restrict__ bias1, float* __restrict__ h) {
    __shared__ float c1[R_TOT * NB];
    for (int q = threadIdx.x; q < R_TOT * NB; q += blockDim.x) c1[q] = comps1[q];
    __syncthreads();
    int t = blockIdx.x * blockDim.x + threadIdx.x;
    int s = t >> 4, e = t & 15;
    int beg = off[s], end = off[s + 1];
    float acc = 0.f;
    for (int j = beg; j < end; j++) {
        int2 rec = recs[j];
        int o = rec.x & 0xFFFF, r = rec.x >> 16;
        float v = __int_as_float(rec.y);
        const float* cr = &c1[r * NB];
        float w = 0.f;
#pragma unroll 8
        for (int b = 0; b < NB; b++) w += cr[b] * bases1[(size_t)b * NE_COL + o * EMB + e];
        acc += v * w;
    }
    h[t] = fmaxf(acc + bias1[e], 0.f);
}

// ---- K7: layer-2 gather, no shfl: all 16 lanes of an edge-group load the ----
// same 64B h[o,:] row (L1 broadcast) and dot it with their w2 column from LDS.
#define W2C 20
#define W2R (16 * W2C + 4)    // 324
__global__ void k_l2_gather(const int* __restrict__ off, const int2* __restrict__ recs,
                            const float* __restrict__ h, const float* __restrict__ w2t,
                            const float* __restrict__ bias2, float* __restrict__ out) {
    __shared__ __align__(16) float w2s[R_TOT * W2R];   // 53,136 B -> 3 blocks/CU @512
    for (int q = threadIdx.x; q < R_TOT * (EMB * NCLS); q += blockDim.x) {
        int r = q >> 8;
        int x = q & 255;
        int c = x >> 4, e = x & 15;
        w2s[r * W2R + c * W2C + e] = w2t[q];
    }
    __syncthreads();
    int t = blockIdx.x * blockDim.x + threadIdx.x;
    if (t >= NE_COL) return;
    int s = t >> 4, c = t & 15;
    int beg = off[s], end = off[s + 1];
    int cbase = c * W2C;
    float acc = 0.f;
    int j = beg;
    for (; j + 1 < end; j += 2) {
        int2 ra = recs[j], rb = recs[j + 1];
        const float4* ha = (const float4*)(h + (size_t)(ra.x & 0xFFFF) * EMB);
        const float4* hb = (const float4*)(h + (size_t)(rb.x & 0xFFFF) * EMB);
        float4 h0 = ha[0], h1 = ha[1], h2 = ha[2], h3 = ha[3];
        float4 g0 = hb[0], g1 = hb[1], g2 = hb[2], g3 = hb[3];
        const float4* wa = (const float4*)&w2s[(ra.x >> 16) * W2R + cbase];
        const float4* wb = (const float4*)&w2s[(rb.x >> 16) * W2R + cbase];
        float4 a0 = wa[0], a1 = wa[1], a2 = wa[2], a3 = wa[3];
        float4 b0 = wb[0], b1 = wb[1], b2 = wb[2], b3 = wb[3];
        float da, db;
        da  = h0.x * a0.x; da = fmaf(h0.y, a0.y, da); da = fmaf(h0.z, a0.z, da); da = fmaf(h0.w, a0.w, da);
        da = fmaf(h1.x, a1.x, da); da = fmaf(h1.y, a1.y, da); da = fmaf(h1.z, a1.z, da); da = fmaf(h1.w, a1.w, da);
        da = fmaf(h2.x, a2.x, da); da = fmaf(h2.y, a2.y, da); da = fmaf(h2.z, a2.z, da); da = fmaf(h2.w, a2.w, da);
        da = fmaf(h3.x, a3.x, da); da = fmaf(h3.y, a3.y, da); da = fmaf(h3.z, a3.z, da); da = fmaf(h3.w, a3.w, da);
        db  = g0.x * b0.x; db = fmaf(g0.y, b0.y, db); db = fmaf(g0.z, b0.z, db); db = fmaf(g0.w, b0.w, db);
        db = fmaf(g1.x, b1.x, db); db = fmaf(g1.y, b1.y, db); db = fmaf(g1.z, b1.z, db); db = fmaf(g1.w, b1.w, db);
        db = fmaf(g2.x, b2.x, db); db = fmaf(g2.y, b2.y, db); db = fmaf(g2.z, b2.z, db); db = fmaf(g2.w, b2.w, db);
        db = fmaf(g3.x, b3.x, db); db = fmaf(g3.y, b3.y, db); db = fmaf(g3.z, b3.z, db); db = fmaf(g3.w, b3.w, db);
        acc = fmaf(__int_as_float(ra.y), da, acc);
        acc = fmaf(__int_as_float(rb.y), db, acc);
    }
    for (; j < end; j++) {
        int2 ra = recs[j];
        const float4* ha = (const float4*)(h + (size_t)(ra.x & 0xFFFF) * EMB);
        float4 h0 = ha[0], h1 = ha[1], h2 = ha[2], h3 = ha[3];
        const float4* wa = (const float4*)&w2s[(ra.x >> 16) * W2R + cbase];
        float4 a0 = wa[0], a1 = wa[1], a2 = wa[2], a3 = wa[3];
        float da;
        da  = h0.x * a0.x; da = fmaf(h0.y, a0.y, da); da = fmaf(h0.z, a0.z, da); da = fmaf(h0.w, a0.w, da);
        da = fmaf(h1.x, a1.x, da); da = fmaf(h1.y, a1.y, da); da = fmaf(h1.z, a1.z, da); da = fmaf(h1.w, a1.w, da);
        da = fmaf(h2.x, a2.x, da); da = fmaf(h2.y, a2.y, da); da = fmaf(h2.z, a2.z, da); da = fmaf(h2.w, a2.w, da);
        da = fmaf(h3.x, a3.x, da); da = fmaf(h3.y, a3.y, da); da = fmaf(h3.z, a3.z, da); da = fmaf(h3.w, a3.w, da);
        acc = fmaf(__int_as_float(ra.y), da, acc);
    }
    out[s * NCLS + c] = acc + bias2[c];
}

static inline size_t align64(size_t x) { return (x + 63) & ~(size_t)63; }

extern "C" void kernel_launch(void* const* d_in, const int* in_sizes, int n_in,
                              void* d_out, int out_size, void* d_ws, size_t ws_size,
                              hipStream_t stream) {
    const int*   src    = (const int*)d_in[0];
    const int*   dst    = (const int*)d_in[1];
    const int*   rel    = (const int*)d_in[2];
    const float* comps1 = (const float*)d_in[3];
    const float* bases1 = (const float*)d_in[4];
    const float* comps2 = (const float*)d_in[5];
    const float* bases2 = (const float*)d_in[6];
    const float* bias1  = (const float*)d_in[7];
    const float* bias2  = (const float*)d_in[8];
    float* out = (float*)d_out;
    (void)in_sizes; (void)n_in; (void)out_size;

    char* ws = (char*)d_ws;
    size_t off_b = 0;
    // w1 (bf16, 65.6 MB) first; cnt2 (16.4MB) + rank (4.2MB) alias its head
    // (both dead before k_w1 writes w1).
    unsigned short* w1 = (unsigned short*)ws;
    int2*  cnt2 = (int2*)ws;
    int*   rank = (int*)(ws + align64((size_t)R_TOT * N_NODES * 8));
    off_b = align64((size_t)R_TOT * NE_COL * 2);              // 65.6 MB
    int*   deg  = (int*)(ws + off_b);  off_b = align64(off_b + (size_t)N_NODES * 4);
    int*   off  = (int*)(ws + off_b);  off_b = align64(off_b + (size_t)(N_NODES + 1) * 4);
    int*   bsum = (int*)(ws + off_b);  off_b = align64(off_b + (size_t)256 * 4);
    int2*  recs = (int2*)(ws + off_b); off_b = align64(off_b + (size_t)E_TOT * 8);
    float* h    = (float*)(ws + off_b); off_b = align64(off_b + (size_t)NE_COL * 4);
    float* w2t  = (float*)(ws + off_b); off_b = align64(off_b + (size_t)R_TOT * EMB * NCLS * 4);
    const bool materialize_w1 = (ws_size >= off_b);
    if (!materialize_w1) {
        off_b = 0;
        cnt2 = (int2*)(ws + off_b);  off_b = align64(off_b + (size_t)R_TOT * N_NODES * 8);
        rank = (int*)(ws + off_b);   off_b = align64(off_b + (size_t)E_TOT * 4);
        deg  = (int*)(ws + off_b);   off_b = align64(off_b + (size_t)N_NODES * 4);
        off  = (int*)(ws + off_b);   off_b = align64(off_b + (size_t)(N_NODES + 1) * 4);
        bsum = (int*)(ws + off_b);   off_b = align64(off_b + (size_t)256 * 4);
        recs = (int2*)(ws + off_b);  off_b = align64(off_b + (size_t)E_TOT * 8);
        h    = (float*)(ws + off_b); off_b = align64(off_b + (size_t)NE_COL * 4);
        w2t  = (float*)(ws + off_b); off_b = align64(off_b + (size_t)R_TOT * EMB * NCLS * 4);
    }

    // zero counts (.x of cnt2; .y overwritten by k_degA)
    hipMemsetAsync(cnt2, 0, (size_t)R_TOT * N_NODES * 8, stream);

    const int BLK = 256;
    const int g_edge = (E_TOT + BLK - 1) / BLK;           // 4102
    const int g_w1   = (NE_COL / 4) / W1_COLS;            // 3125 (exact)
    const int g_l1   = (N_NODES * 8 + BLK - 1) / BLK;     // 1563
    const int g_l1f  = (N_NODES * 16) / BLK;              // 3125 (fallback, 16-lane)
    const int g_l2   = (NE_COL + 511) / 512;              // 1563

    k_count<<<g_edge, BLK, 0, stream>>>(src, dst, rel, cnt2, rank);
    k_degA<<<NBLK_N, 256, 0, stream>>>(cnt2, deg, bsum);
    k_degB<<<1, 256, 0, stream>>>(bsum);
    k_degC<<<NBLK_N, 256, 0, stream>>>(deg, bsum, off);
    k_fill<<<g_edge, BLK, 0, stream>>>(src, dst, rel, cnt2, rank, off, recs);
    k_w2<<<R_TOT, EMB * NCLS, 0, stream>>>(comps2, bases2, w2t);

    if (materialize_w1) {
        k_w1<<<g_w1, 512, 0, stream>>>(comps1, bases1, (uint2*)w1);  // overwrites cnt2/rank (dead)
        k_l1_gather<<<g_l1, BLK, 0, stream>>>(off, recs, (const unsigned*)w1, bias1, h);
    } else {
        k_l1_gather_fly<<<g_l1f, BLK, 0, stream>>>(off, recs, comps1, bases1, bias1, h);
    }

    k_l2_gather<<<g_l2, 512, 0, stream>>>(off, recs, h, w2t, bias2, out);
}

// Round 9
// 412.317 us; speedup vs baseline: 1.0768x; 1.0768x over previous
//
#include <hip/hip_runtime.h>

#define N_NODES 50000
#define N_RELSR 20
#define R_TOT   41          // 2*N_RELSR + 1
#define N_EDGES 500000
#define EMB     16
#define NCLS    16
#define NB      40
#define E_TOT   (2 * N_EDGES + N_NODES)   // 1,050,000
#define NE_COL  (N_NODES * EMB)           // 800,000
#define NBLK_N  ((N_NODES + 255) / 256)   // 196

// f32 -> bf16 round-to-nearest-even (manual, no header dependency)
__device__ __forceinline__ unsigned short f2bf(float f) {
    unsigned u = __float_as_uint(f);
    u += 0x7FFFu + ((u >> 16) & 1u);
    return (unsigned short)(u >> 16);
}

// decode enriched edge i -> (s, o, r)
__device__ __forceinline__ void edge_decode(int i, const int* __restrict__ src,
                                            const int* __restrict__ dst,
                                            const int* __restrict__ rel,
                                            int& s, int& o, int& r) {
    if (i < N_EDGES) {
        s = src[i]; o = dst[i]; r = rel[i];
    } else if (i < 2 * N_EDGES) {
        int j = i - N_EDGES;
        s = dst[j]; o = src[j]; r = rel[j] + N_RELSR;
    } else {
        int n = i - 2 * N_EDGES;
        s = n; o = n; r = 2 * N_RELSR;
    }
}

// cnt2[idx] = { count, local r-prefix within node s }

// ---- K1: segment counts; also record each edge's rank within its segment ---
__global__ void k_count(const int* __restrict__ src, const int* __restrict__ dst,
                        const int* __restrict__ rel, int2* __restrict__ cnt2,
                        int* __restrict__ rank) {
    int i = blockIdx.x * blockDim.x + threadIdx.x;
    if (i >= E_TOT) return;
    int s, o, r;
    edge_decode(i, src, dst, rel, s, o, r);
    rank[i] = atomicAdd(&cnt2[r * N_NODES + s].x, 1);
}

// ---- K2a: deg[s] = sum_r cnt[r,s]; local r-prefix into .y; per-block sums ---
__global__ void k_degA(int2* __restrict__ cnt2, int* __restrict__ deg,
                       int* __restrict__ bsum) {
    __shared__ int red[256];
    int t = threadIdx.x;
    int s = blockIdx.x * 256 + t;
    int run = 0;
    if (s < N_NODES) {
        for (int r = 0; r < R_TOT; r++) {
            int idx = r * N_NODES + s;
            int2 val = cnt2[idx];
            val.y = run;              // local exclusive prefix over r
            cnt2[idx] = val;
            run += val.x;
        }
        deg[s] = run;
    }
    red[t] = run;
    __syncthreads();
    for (int st = 128; st > 0; st >>= 1) {
        if (t < st) red[t] += red[t + st];
        __syncthreads();
    }
    if (t == 0) bsum[blockIdx.x] = red[0];
}

// ---- K2b: exclusive scan of 196 block sums (single tiny block) --------------
__global__ void k_degB(int* __restrict__ bsum) {
    __shared__ int sh[256];
    int t = threadIdx.x;
    int v = (t < NBLK_N) ? bsum[t] : 0;
    sh[t] = v;
    __syncthreads();
    for (int d = 1; d < 256; d <<= 1) {
        int x = (t >= d) ? sh[t - d] : 0;
        __syncthreads();
        sh[t] += x;
        __syncthreads();
    }
    if (t < NBLK_N) bsum[t] = sh[t] - v;   // exclusive
}

// ---- K2c: block-local scan of deg -> off (global CSR offsets) ---------------
__global__ void k_degC(const int* __restrict__ deg, const int* __restrict__ bsum,
                       int* __restrict__ off) {
    __shared__ int sh[256];
    int t = threadIdx.x;
    int s = blockIdx.x * 256 + t;
    int d = (s < N_NODES) ? deg[s] : 0;
    sh[t] = d;
    __syncthreads();
    for (int dd = 1; dd < 256; dd <<= 1) {
        int x = (t >= dd) ? sh[t - dd] : 0;
        __syncthreads();
        sh[t] += x;
        __syncthreads();
    }
    int excl = sh[t] - d + bsum[blockIdx.x];
    if (s < N_NODES) off[s] = excl;
    if (s == 0) off[N_NODES] = E_TOT;
}

// ---- K3: fill CSR records {(r<<16)|o, v} sorted by (s, r); no atomics -------
__global__ void k_fill(const int* __restrict__ src, const int* __restrict__ dst,
                       const int* __restrict__ rel, const int2* __restrict__ cnt2,
                       const int* __restrict__ rank, const int* __restrict__ off,
                       int2* __restrict__ recs) {
    int i = blockIdx.x * blockDim.x + threadIdx.x;
    if (i >= E_TOT) return;
    int s, o, r;
    edge_decode(i, src, dst, rel, s, o, r);
    int2 cr = cnt2[r * N_NODES + s];
    float v = 1.0f / (float)cr.x;
    recs[off[s] + cr.y + rank[i]] = make_int2((r << 16) | o, __float_as_int(v));
}

// ---- K4: w1[r,n,e] = sum_b comps1[r,b] * bases1[b,n,e]  -> bf16 -------------
// Round-6 form: measured best (83 us). The compiler interchanges to r-outer
// with 44 VGPR and L1-served bases re-reads; every attempt to restructure
// (r-tiled regs r7, LDS-staged r8) measured worse. Do not touch.
__global__ void __launch_bounds__(256, 2)
k_w1(const float* __restrict__ comps1, const float* __restrict__ bases1,
     unsigned* __restrict__ w1p) {
    int j = blockIdx.x * blockDim.x + threadIdx.x;
    if (j >= NE_COL / 2) return;
    const float2* b2 = (const float2*)bases1;
    float2 acc[R_TOT];
#pragma unroll
    for (int r = 0; r < R_TOT; r++) { acc[r].x = 0.f; acc[r].y = 0.f; }
    for (int b = 0; b < NB; b++) {
        float2 bb = b2[(size_t)b * (NE_COL / 2) + j];
#pragma unroll
        for (int r = 0; r < R_TOT; r++) {
            float cc = comps1[r * NB + b];
            acc[r].x += cc * bb.x;
            acc[r].y += cc * bb.y;
        }
    }
#pragma unroll
    for (int r = 0; r < R_TOT; r++) {
        unsigned pk = ((unsigned)f2bf(acc[r].y) << 16) | (unsigned)f2bf(acc[r].x);
        w1p[(size_t)r * (NE_COL / 2) + j] = pk;
    }
}

// ---- K5: w2t[r,c,e] = sum_b comps2[r,b] * bases2[b,e,c]  (transposed) -------
__global__ void k_w2(const float* __restrict__ comps2, const float* __restrict__ bases2,
                     float* __restrict__ w2t) {
    int r = blockIdx.x;        // 41 blocks
    int t = threadIdx.x;       // 256 = NCLS*EMB, t = c*16+e
    int c = t >> 4, e = t & 15;
    float acc = 0.f;
#pragma unroll 8
    for (int b = 0; b < NB; b++) acc += comps2[r * NB + b] * bases2[b * (EMB * NCLS) + e * NCLS + c];
    w2t[r * (EMB * NCLS) + t] = acc;
}

// ---- K6: layer-1 gather, 8 lanes/edge, 8-edge unroll ------------------------
__global__ void k_l1_gather(const int* __restrict__ off, const int2* __restrict__ recs,
                            const unsigned* __restrict__ w1p,
                            const float* __restrict__ bias1, float* __restrict__ h) {
    int t = blockIdx.x * blockDim.x + threadIdx.x;     // N_NODES*8
    if (t >= N_NODES * 8) return;
    int s = t >> 3, e2 = t & 7;
    int beg = off[s], end = off[s + 1];
    float ax = 0.f, ay = 0.f;
    int j = beg;
    for (; j + 7 < end; j += 8) {
        int2 rc[8];
        unsigned p[8];
#pragma unroll
        for (int k = 0; k < 8; k++) rc[k] = recs[j + k];
#pragma unroll
        for (int k = 0; k < 8; k++)
            p[k] = w1p[(size_t)(rc[k].x >> 16) * (NE_COL / 2) + (rc[k].x & 0xFFFF) * 8 + e2];
#pragma unroll
        for (int k = 0; k < 8; k++) {
            float v = __int_as_float(rc[k].y);
            ax = fmaf(v, __uint_as_float(p[k] << 16), ax);
            ay = fmaf(v, __uint_as_float(p[k] & 0xFFFF0000u), ay);
        }
    }
    for (; j < end; j++) {
        int2 rc = recs[j];
        unsigned p = w1p[(size_t)(rc.x >> 16) * (NE_COL / 2) + (rc.x & 0xFFFF) * 8 + e2];
        float v = __int_as_float(rc.y);
        ax = fmaf(v, __uint_as_float(p << 16), ax);
        ay = fmaf(v, __uint_as_float(p & 0xFFFF0000u), ay);
    }
    float2 res;
    res.x = fmaxf(ax + bias1[2 * e2], 0.f);
    res.y = fmaxf(ay + bias1[2 * e2 + 1], 0.f);
    ((float2*)h)[t] = res;
}

// ---- K6-alt (fallback if ws too small for w1): on-the-fly basis contraction -
__global__ void k_l1_gather_fly(const int* __restrict__ off, const int2* __restrict__ recs,
                                const float* __restrict__ comps1,
                                const float* __restrict__ bases1,
                                const float* __restrict__ bias1, float* __restrict__ h) {
    __shared__ float c1[R_TOT * NB];
    for (int q = threadIdx.x; q < R_TOT * NB; q += blockDim.x) c1[q] = comps1[q];
    __syncthreads();
    int t = blockIdx.x * blockDim.x + threadIdx.x;
    int s = t >> 4, e = t & 15;
    int beg = off[s], end = off[s + 1];
    float acc = 0.f;
    for (int j = beg; j < end; j++) {
        int2 rec = recs[j];
        int o = rec.x & 0xFFFF, r = rec.x >> 16;
        float v = __int_as_float(rec.y);
        const float* cr = &c1[r * NB];
        float w = 0.f;
#pragma unroll 8
        for (int b = 0; b < NB; b++) w += cr[b] * bases1[(size_t)b * NE_COL + o * EMB + e];
        acc += v * w;
    }
    h[t] = fmaxf(acc + bias1[e], 0.f);
}

// ---- K7: layer-2 gather, no shfl, 4-edge unroll -----------------------------
// All 16 lanes of an edge-group load the same 64B h[o,:] row (L1 broadcast)
// and dot it with their w2 column from LDS (c-stride 20: only free 2-way).
#define W2C 20
#define W2R (16 * W2C + 4)    // 324
__device__ __forceinline__ float l2_edge(int2 ra, const float* __restrict__ h,
                                         const float* w2s, int cbase) {
    const float4* ha = (const float4*)(h + (size_t)(ra.x & 0xFFFF) * EMB);
    const float4* wa = (const float4*)&w2s[(ra.x >> 16) * W2R + cbase];
    float4 h0 = ha[0], h1 = ha[1], h2 = ha[2], h3 = ha[3];
    float4 a0 = wa[0], a1 = wa[1], a2 = wa[2], a3 = wa[3];
    float da;
    da  = h0.x * a0.x; da = fmaf(h0.y, a0.y, da); da = fmaf(h0.z, a0.z, da); da = fmaf(h0.w, a0.w, da);
    da = fmaf(h1.x, a1.x, da); da = fmaf(h1.y, a1.y, da); da = fmaf(h1.z, a1.z, da); da = fmaf(h1.w, a1.w, da);
    da = fmaf(h2.x, a2.x, da); da = fmaf(h2.y, a2.y, da); da = fmaf(h2.z, a2.z, da); da = fmaf(h2.w, a2.w, da);
    da = fmaf(h3.x, a3.x, da); da = fmaf(h3.y, a3.y, da); da = fmaf(h3.z, a3.z, da); da = fmaf(h3.w, a3.w, da);
    return __int_as_float(ra.y) * da;
}

__global__ void k_l2_gather(const int* __restrict__ off, const int2* __restrict__ recs,
                            const float* __restrict__ h, const float* __restrict__ w2t,
                            const float* __restrict__ bias2, float* __restrict__ out) {
    __shared__ __align__(16) float w2s[R_TOT * W2R];   // 53,136 B -> 3 blocks/CU @512
    for (int q = threadIdx.x; q < R_TOT * (EMB * NCLS); q += blockDim.x) {
        int r = q >> 8;
        int x = q & 255;
        int c = x >> 4, e = x & 15;
        w2s[r * W2R + c * W2C + e] = w2t[q];
    }
    __syncthreads();
    int t = blockIdx.x * blockDim.x + threadIdx.x;
    if (t >= NE_COL) return;
    int s = t >> 4, c = t & 15;
    int beg = off[s], end = off[s + 1];
    int cbase = c * W2C;
    float acc = 0.f;
    int j = beg;
    for (; j + 3 < end; j += 4) {
        int2 r0 = recs[j], r1 = recs[j + 1], r2 = recs[j + 2], r3 = recs[j + 3];
        float t0 = l2_edge(r0, h, w2s, cbase);
        float t1 = l2_edge(r1, h, w2s, cbase);
        float t2 = l2_edge(r2, h, w2s, cbase);
        float t3 = l2_edge(r3, h, w2s, cbase);
        acc += (t0 + t1) + (t2 + t3);
    }
    for (; j < end; j++) {
        acc += l2_edge(recs[j], h, w2s, cbase);
    }
    out[s * NCLS + c] = acc + bias2[c];
}

static inline size_t align64(size_t x) { return (x + 63) & ~(size_t)63; }

extern "C" void kernel_launch(void* const* d_in, const int* in_sizes, int n_in,
                              void* d_out, int out_size, void* d_ws, size_t ws_size,
                              hipStream_t stream) {
    const int*   src    = (const int*)d_in[0];
    const int*   dst    = (const int*)d_in[1];
    const int*   rel    = (const int*)d_in[2];
    const float* comps1 = (const float*)d_in[3];
    const float* bases1 = (const float*)d_in[4];
    const float* comps2 = (const float*)d_in[5];
    const float* bases2 = (const float*)d_in[6];
    const float* bias1  = (const float*)d_in[7];
    const float* bias2  = (const float*)d_in[8];
    float* out = (float*)d_out;
    (void)in_sizes; (void)n_in; (void)out_size;

    char* ws = (char*)d_ws;
    size_t off_b = 0;
    // w1 (bf16, 65.6 MB) first; cnt2 (16.4MB) + rank (4.2MB) alias its head
    // (both dead before k_w1 writes w1).
    unsigned short* w1 = (unsigned short*)ws;
    int2*  cnt2 = (int2*)ws;
    int*   rank = (int*)(ws + align64((size_t)R_TOT * N_NODES * 8));
    off_b = align64((size_t)R_TOT * NE_COL * 2);              // 65.6 MB
    int*   deg  = (int*)(ws + off_b);  off_b = align64(off_b + (size_t)N_NODES * 4);
    int*   off  = (int*)(ws + off_b);  off_b = align64(off_b + (size_t)(N_NODES + 1) * 4);
    int*   bsum = (int*)(ws + off_b);  off_b = align64(off_b + (size_t)256 * 4);
    int2*  recs = (int2*)(ws + off_b); off_b = align64(off_b + (size_t)E_TOT * 8);
    float* h    = (float*)(ws + off_b); off_b = align64(off_b + (size_t)NE_COL * 4);
    float* w2t  = (float*)(ws + off_b); off_b = align64(off_b + (size_t)R_TOT * EMB * NCLS * 4);
    const bool materialize_w1 = (ws_size >= off_b);
    if (!materialize_w1) {
        off_b = 0;
        cnt2 = (int2*)(ws + off_b);  off_b = align64(off_b + (size_t)R_TOT * N_NODES * 8);
        rank = (int*)(ws + off_b);   off_b = align64(off_b + (size_t)E_TOT * 4);
        deg  = (int*)(ws + off_b);   off_b = align64(off_b + (size_t)N_NODES * 4);
        off  = (int*)(ws + off_b);   off_b = align64(off_b + (size_t)(N_NODES + 1) * 4);
        bsum = (int*)(ws + off_b);   off_b = align64(off_b + (size_t)256 * 4);
        recs = (int2*)(ws + off_b);  off_b = align64(off_b + (size_t)E_TOT * 8);
        h    = (float*)(ws + off_b); off_b = align64(off_b + (size_t)NE_COL * 4);
        w2t  = (float*)(ws + off_b); off_b = align64(off_b + (size_t)R_TOT * EMB * NCLS * 4);
    }

    // zero counts (.x of cnt2; .y overwritten by k_degA)
    hipMemsetAsync(cnt2, 0, (size_t)R_TOT * N_NODES * 8, stream);

    const int BLK = 256;
    const int g_edge = (E_TOT + BLK - 1) / BLK;           // 4102
    const int g_w1   = (NE_COL / 2 + BLK - 1) / BLK;      // 1563
    const int g_l1   = (N_NODES * 8 + BLK - 1) / BLK;     // 1563
    const int g_l1f  = (N_NODES * 16) / BLK;              // 3125 (fallback, 16-lane)
    const int g_l2   = (NE_COL + 511) / 512;              // 1563

    k_count<<<g_edge, BLK, 0, stream>>>(src, dst, rel, cnt2, rank);
    k_degA<<<NBLK_N, 256, 0, stream>>>(cnt2, deg, bsum);
    k_degB<<<1, 256, 0, stream>>>(bsum);
    k_degC<<<NBLK_N, 256, 0, stream>>>(deg, bsum, off);
    k_fill<<<g_edge, BLK, 0, stream>>>(src, dst, rel, cnt2, rank, off, recs);
    k_w2<<<R_TOT, EMB * NCLS, 0, stream>>>(comps2, bases2, w2t);

    if (materialize_w1) {
        k_w1<<<g_w1, BLK, 0, stream>>>(comps1, bases1, (unsigned*)w1);  // overwrites cnt2/rank (dead)
        k_l1_gather<<<g_l1, BLK, 0, stream>>>(off, recs, (const unsigned*)w1, bias1, h);
    } else {
        k_l1_gather_fly<<<g_l1f, BLK, 0, stream>>>(off, recs, comps1, bases1, bias1, h);
    }

    k_l2_gather<<<g_l2, 512, 0, stream>>>(off, recs, h, w2t, bias2, out);
}

// Round 10
// 407.145 us; speedup vs baseline: 1.0904x; 1.0127x over previous
//
#include <hip/hip_runtime.h>

#define N_NODES 50000
#define N_RELSR 20
#define R_TOT   41          // 2*N_RELSR + 1
#define N_EDGES 500000
#define EMB     16
#define NCLS    16
#define NB      40
#define E_TOT   (2 * N_EDGES + N_NODES)   // 1,050,000
#define NE_COL  (N_NODES * EMB)           // 800,000
#define NBLK_N  ((N_NODES + 255) / 256)   // 196

// f32 -> bf16 round-to-nearest-even (manual, no header dependency)
__device__ __forceinline__ unsigned short f2bf(float f) {
    unsigned u = __float_as_uint(f);
    u += 0x7FFFu + ((u >> 16) & 1u);
    return (unsigned short)(u >> 16);
}

// decode enriched edge i -> (s, o, r)
__device__ __forceinline__ void edge_decode(int i, const int* __restrict__ src,
                                            const int* __restrict__ dst,
                                            const int* __restrict__ rel,
                                            int& s, int& o, int& r) {
    if (i < N_EDGES) {
        s = src[i]; o = dst[i]; r = rel[i];
    } else if (i < 2 * N_EDGES) {
        int j = i - N_EDGES;
        s = dst[j]; o = src[j]; r = rel[j] + N_RELSR;
    } else {
        int n = i - 2 * N_EDGES;
        s = n; o = n; r = 2 * N_RELSR;
    }
}

// cnt2[idx] = { count, local r-prefix within node s }

// ---- K1: segment counts; also record each edge's rank within its segment ---
__global__ void k_count(const int* __restrict__ src, const int* __restrict__ dst,
                        const int* __restrict__ rel, int2* __restrict__ cnt2,
                        int* __restrict__ rank) {
    int i = blockIdx.x * blockDim.x + threadIdx.x;
    if (i >= E_TOT) return;
    int s, o, r;
    edge_decode(i, src, dst, rel, s, o, r);
    rank[i] = atomicAdd(&cnt2[r * N_NODES + s].x, 1);
}

// ---- K2a: deg[s] = sum_r cnt[r,s]; local r-prefix into .y; per-block sums ---
__global__ void k_degA(int2* __restrict__ cnt2, int* __restrict__ deg,
                       int* __restrict__ bsum) {
    __shared__ int red[256];
    int t = threadIdx.x;
    int s = blockIdx.x * 256 + t;
    int run = 0;
    if (s < N_NODES) {
        for (int r = 0; r < R_TOT; r++) {
            int idx = r * N_NODES + s;
            int2 val = cnt2[idx];
            val.y = run;              // local exclusive prefix over r
            cnt2[idx] = val;
            run += val.x;
        }
        deg[s] = run;
    }
    red[t] = run;
    __syncthreads();
    for (int st = 128; st > 0; st >>= 1) {
        if (t < st) red[t] += red[t + st];
        __syncthreads();
    }
    if (t == 0) bsum[blockIdx.x] = red[0];
}

// ---- K2b: exclusive scan of 196 block sums (single tiny block) --------------
__global__ void k_degB(int* __restrict__ bsum) {
    __shared__ int sh[256];
    int t = threadIdx.x;
    int v = (t < NBLK_N) ? bsum[t] : 0;
    sh[t] = v;
    __syncthreads();
    for (int d = 1; d < 256; d <<= 1) {
        int x = (t >= d) ? sh[t - d] : 0;
        __syncthreads();
        sh[t] += x;
        __syncthreads();
    }
    if (t < NBLK_N) bsum[t] = sh[t] - v;   // exclusive
}

// ---- K2c: block-local scan of deg -> off (global CSR offsets) ---------------
__global__ void k_degC(const int* __restrict__ deg, const int* __restrict__ bsum,
                       int* __restrict__ off) {
    __shared__ int sh[256];
    int t = threadIdx.x;
    int s = blockIdx.x * 256 + t;
    int d = (s < N_NODES) ? deg[s] : 0;
    sh[t] = d;
    __syncthreads();
    for (int dd = 1; dd < 256; dd <<= 1) {
        int x = (t >= dd) ? sh[t - dd] : 0;
        __syncthreads();
        sh[t] += x;
        __syncthreads();
    }
    int excl = sh[t] - d + bsum[blockIdx.x];
    if (s < N_NODES) off[s] = excl;
    if (s == 0) off[N_NODES] = E_TOT;
}

// ---- K3: fill CSR records {(r<<16)|o, v} sorted by (s, r); no atomics -------
__global__ void k_fill(const int* __restrict__ src, const int* __restrict__ dst,
                       const int* __restrict__ rel, const int2* __restrict__ cnt2,
                       const int* __restrict__ rank, const int* __restrict__ off,
                       int2* __restrict__ recs) {
    int i = blockIdx.x * blockDim.x + threadIdx.x;
    if (i >= E_TOT) return;
    int s, o, r;
    edge_decode(i, src, dst, rel, s, o, r);
    int2 cr = cnt2[r * N_NODES + s];
    float v = 1.0f / (float)cr.x;
    recs[off[s] + cr.y + rank[i]] = make_int2((r << 16) | o, __float_as_int(v));
}

// ---- K4: w1[r,n,e] = sum_b comps1[r,b] * bases1[b,n,e]  -> bf16 -------------
// Round-6 form: measured best (80-83 us). The compiler interchanges to r-outer
// with 44 VGPR and L1-served bases re-reads; every attempt to restructure
// (r-tiled regs r7, LDS-staged r8, wider loads) measured worse. Do not touch.
__global__ void __launch_bounds__(256, 2)
k_w1(const float* __restrict__ comps1, const float* __restrict__ bases1,
     unsigned* __restrict__ w1p) {
    int j = blockIdx.x * blockDim.x + threadIdx.x;
    if (j >= NE_COL / 2) return;
    const float2* b2 = (const float2*)bases1;
    float2 acc[R_TOT];
#pragma unroll
    for (int r = 0; r < R_TOT; r++) { acc[r].x = 0.f; acc[r].y = 0.f; }
    for (int b = 0; b < NB; b++) {
        float2 bb = b2[(size_t)b * (NE_COL / 2) + j];
#pragma unroll
        for (int r = 0; r < R_TOT; r++) {
            float cc = comps1[r * NB + b];
            acc[r].x += cc * bb.x;
            acc[r].y += cc * bb.y;
        }
    }
#pragma unroll
    for (int r = 0; r < R_TOT; r++) {
        unsigned pk = ((unsigned)f2bf(acc[r].y) << 16) | (unsigned)f2bf(acc[r].x);
        w1p[(size_t)r * (NE_COL / 2) + j] = pk;
    }
}

// ---- K5: w2p[r,c,ep] = packed bf16 pair (e=2ep, 2ep+1) of ---------------------
//          sum_b comps2[r,b] * bases2[b,e,c]
__global__ void k_w2(const float* __restrict__ comps2, const float* __restrict__ bases2,
                     unsigned* __restrict__ w2p) {
    int r = blockIdx.x;        // 41 blocks
    int t = threadIdx.x;       // 128 = NCLS*EMB/2, t = c*8+ep
    int c = t >> 3, ep = t & 7;
    int e0 = 2 * ep, e1 = 2 * ep + 1;
    float a0 = 0.f, a1 = 0.f;
#pragma unroll 8
    for (int b = 0; b < NB; b++) {
        float cc = comps2[r * NB + b];
        a0 = fmaf(cc, bases2[b * (EMB * NCLS) + e0 * NCLS + c], a0);
        a1 = fmaf(cc, bases2[b * (EMB * NCLS) + e1 * NCLS + c], a1);
    }
    w2p[r * 128 + t] = ((unsigned)f2bf(a1) << 16) | (unsigned)f2bf(a0);
}

// ---- K6: layer-1 gather, 8 lanes/edge, 8-edge unroll ------------------------
__global__ void k_l1_gather(const int* __restrict__ off, const int2* __restrict__ recs,
                            const unsigned* __restrict__ w1p,
                            const float* __restrict__ bias1, float* __restrict__ h) {
    int t = blockIdx.x * blockDim.x + threadIdx.x;     // N_NODES*8
    if (t >= N_NODES * 8) return;
    int s = t >> 3, e2 = t & 7;
    int beg = off[s], end = off[s + 1];
    float ax = 0.f, ay = 0.f;
    int j = beg;
    for (; j + 7 < end; j += 8) {
        int2 rc[8];
        unsigned p[8];
#pragma unroll
        for (int k = 0; k < 8; k++) rc[k] = recs[j + k];
#pragma unroll
        for (int k = 0; k < 8; k++)
            p[k] = w1p[(size_t)(rc[k].x >> 16) * (NE_COL / 2) + (rc[k].x & 0xFFFF) * 8 + e2];
#pragma unroll
        for (int k = 0; k < 8; k++) {
            float v = __int_as_float(rc[k].y);
            ax = fmaf(v, __uint_as_float(p[k] << 16), ax);
            ay = fmaf(v, __uint_as_float(p[k] & 0xFFFF0000u), ay);
        }
    }
    for (; j < end; j++) {
        int2 rc = recs[j];
        unsigned p = w1p[(size_t)(rc.x >> 16) * (NE_COL / 2) + (rc.x & 0xFFFF) * 8 + e2];
        float v = __int_as_float(rc.y);
        ax = fmaf(v, __uint_as_float(p << 16), ax);
        ay = fmaf(v, __uint_as_float(p & 0xFFFF0000u), ay);
    }
    float2 res;
    res.x = fmaxf(ax + bias1[2 * e2], 0.f);
    res.y = fmaxf(ay + bias1[2 * e2 + 1], 0.f);
    ((float2*)h)[t] = res;
}

// ---- K6-alt (fallback if ws too small for w1): on-the-fly basis contraction -
__global__ void k_l1_gather_fly(const int* __restrict__ off, const int2* __restrict__ recs,
                                const float* __restrict__ comps1,
                                const float* __restrict__ bases1,
                                const float* __restrict__ bias1, float* __restrict__ h) {
    __shared__ float c1[R_TOT * NB];
    for (int q = threadIdx.x; q < R_TOT * NB; q += blockDim.x) c1[q] = comps1[q];
    __syncthreads();
    int t = blockIdx.x * blockDim.x + threadIdx.x;
    int s = t >> 4, e = t & 15;
    int beg = off[s], end = off[s + 1];
    float acc = 0.f;
    for (int j = beg; j < end; j++) {
        int2 rec = recs[j];
        int o = rec.x & 0xFFFF, r = rec.x >> 16;
        float v = __int_as_float(rec.y);
        const float* cr = &c1[r * NB];
        float w = 0.f;
#pragma unroll 8
        for (int b = 0; b < NB; b++) w += cr[b] * bases1[(size_t)b * NE_COL + o * EMB + e];
        acc += v * w;
    }
    h[t] = fmaxf(acc + bias1[e], 0.f);
}

// ---- K7: layer-2 gather, bf16 w2 in LDS -------------------------------------
// All 16 lanes of an edge-group load the same 64B h[o,:] row (L1 broadcast).
// w2 stored as packed bf16 pairs: [r][c][ep], c-stride 10 uints (lane-c bank
// pattern c*10%32 covers all 16 banks), r-stride 164 uints. 26,896 B LDS ->
// 4 blocks of 512 per CU (~100% occupancy vs 47% with the 53KB f32 tile).
#define W2C2 10
#define W2R2 (16 * W2C2 + 4)    // 164 uints per relation
__device__ __forceinline__ float l2_edge(int2 ra, const float* __restrict__ h,
                                         const unsigned* w2s, int cbase) {
    const float4* ha = (const float4*)(h + (size_t)(ra.x & 0xFFFF) * EMB);
    const unsigned* base = &w2s[(ra.x >> 16) * W2R2 + cbase];
    float4 h0 = ha[0], h1 = ha[1], h2 = ha[2], h3 = ha[3];
    uint2 q0 = *(const uint2*)(base + 0);
    uint2 q1 = *(const uint2*)(base + 2);
    uint2 q2 = *(const uint2*)(base + 4);
    uint2 q3 = *(const uint2*)(base + 6);
    float da;
    da  = h0.x * __uint_as_float(q0.x << 16);
    da = fmaf(h0.y, __uint_as_float(q0.x & 0xFFFF0000u), da);
    da = fmaf(h0.z, __uint_as_float(q0.y << 16), da);
    da = fmaf(h0.w, __uint_as_float(q0.y & 0xFFFF0000u), da);
    da = fmaf(h1.x, __uint_as_float(q1.x << 16), da);
    da = fmaf(h1.y, __uint_as_float(q1.x & 0xFFFF0000u), da);
    da = fmaf(h1.z, __uint_as_float(q1.y << 16), da);
    da = fmaf(h1.w, __uint_as_float(q1.y & 0xFFFF0000u), da);
    da = fmaf(h2.x, __uint_as_float(q2.x << 16), da);
    da = fmaf(h2.y, __uint_as_float(q2.x & 0xFFFF0000u), da);
    da = fmaf(h2.z, __uint_as_float(q2.y << 16), da);
    da = fmaf(h2.w, __uint_as_float(q2.y & 0xFFFF0000u), da);
    da = fmaf(h3.x, __uint_as_float(q3.x << 16), da);
    da = fmaf(h3.y, __uint_as_float(q3.x & 0xFFFF0000u), da);
    da = fmaf(h3.z, __uint_as_float(q3.y << 16), da);
    da = fmaf(h3.w, __uint_as_float(q3.y & 0xFFFF0000u), da);
    return __int_as_float(ra.y) * da;
}

__global__ void k_l2_gather(const int* __restrict__ off, const int2* __restrict__ recs,
                            const float* __restrict__ h, const unsigned* __restrict__ w2p,
                            const float* __restrict__ bias2, float* __restrict__ out) {
    __shared__ __align__(16) unsigned w2s[R_TOT * W2R2];   // 26,896 B
    for (int q = threadIdx.x; q < R_TOT * 128; q += blockDim.x) {
        int r = q >> 7;
        int x = q & 127;
        int c = x >> 3, ep = x & 7;
        w2s[r * W2R2 + c * W2C2 + ep] = w2p[q];
    }
    __syncthreads();
    int t = blockIdx.x * blockDim.x + threadIdx.x;
    if (t >= NE_COL) return;
    int s = t >> 4, c = t & 15;
    int beg = off[s], end = off[s + 1];
    int cbase = c * W2C2;
    float acc = 0.f;
    int j = beg;
    for (; j + 3 < end; j += 4) {
        int2 r0 = recs[j], r1 = recs[j + 1], r2 = recs[j + 2], r3 = recs[j + 3];
        float t0 = l2_edge(r0, h, w2s, cbase);
        float t1 = l2_edge(r1, h, w2s, cbase);
        float t2 = l2_edge(r2, h, w2s, cbase);
        float t3 = l2_edge(r3, h, w2s, cbase);
        acc += (t0 + t1) + (t2 + t3);
    }
    for (; j < end; j++) {
        acc += l2_edge(recs[j], h, w2s, cbase);
    }
    out[s * NCLS + c] = acc + bias2[c];
}

static inline size_t align64(size_t x) { return (x + 63) & ~(size_t)63; }

extern "C" void kernel_launch(void* const* d_in, const int* in_sizes, int n_in,
                              void* d_out, int out_size, void* d_ws, size_t ws_size,
                              hipStream_t stream) {
    const int*   src    = (const int*)d_in[0];
    const int*   dst    = (const int*)d_in[1];
    const int*   rel    = (const int*)d_in[2];
    const float* comps1 = (const float*)d_in[3];
    const float* bases1 = (const float*)d_in[4];
    const float* comps2 = (const float*)d_in[5];
    const float* bases2 = (const float*)d_in[6];
    const float* bias1  = (const float*)d_in[7];
    const float* bias2  = (const float*)d_in[8];
    float* out = (float*)d_out;
    (void)in_sizes; (void)n_in; (void)out_size;

    char* ws = (char*)d_ws;
    size_t off_b = 0;
    // w1 (bf16, 65.6 MB) first; cnt2 (16.4MB) + rank (4.2MB) alias its head
    // (both dead before k_w1 writes w1).
    unsigned short* w1 = (unsigned short*)ws;
    int2*  cnt2 = (int2*)ws;
    int*   rank = (int*)(ws + align64((size_t)R_TOT * N_NODES * 8));
    off_b = align64((size_t)R_TOT * NE_COL * 2);              // 65.6 MB
    int*      deg  = (int*)(ws + off_b);      off_b = align64(off_b + (size_t)N_NODES * 4);
    int*      off  = (int*)(ws + off_b);      off_b = align64(off_b + (size_t)(N_NODES + 1) * 4);
    int*      bsum = (int*)(ws + off_b);      off_b = align64(off_b + (size_t)256 * 4);
    int2*     recs = (int2*)(ws + off_b);     off_b = align64(off_b + (size_t)E_TOT * 8);
    float*    h    = (float*)(ws + off_b);    off_b = align64(off_b + (size_t)NE_COL * 4);
    unsigned* w2p  = (unsigned*)(ws + off_b); off_b = align64(off_b + (size_t)R_TOT * 128 * 4);
    const bool materialize_w1 = (ws_size >= off_b);
    if (!materialize_w1) {
        off_b = 0;
        cnt2 = (int2*)(ws + off_b);     off_b = align64(off_b + (size_t)R_TOT * N_NODES * 8);
        rank = (int*)(ws + off_b);      off_b = align64(off_b + (size_t)E_TOT * 4);
        deg  = (int*)(ws + off_b);      off_b = align64(off_b + (size_t)N_NODES * 4);
        off  = (int*)(ws + off_b);      off_b = align64(off_b + (size_t)(N_NODES + 1) * 4);
        bsum = (int*)(ws + off_b);      off_b = align64(off_b + (size_t)256 * 4);
        recs = (int2*)(ws + off_b);     off_b = align64(off_b + (size_t)E_TOT * 8);
        h    = (float*)(ws + off_b);    off_b = align64(off_b + (size_t)NE_COL * 4);
        w2p  = (unsigned*)(ws + off_b); off_b = align64(off_b + (size_t)R_TOT * 128 * 4);
    }

    // zero counts (.x of cnt2; .y overwritten by k_degA)
    hipMemsetAsync(cnt2, 0, (size_t)R_TOT * N_NODES * 8, stream);

    const int BLK = 256;
    const int g_edge = (E_TOT + BLK - 1) / BLK;           // 4102
    const int g_w1   = (NE_COL / 2 + BLK - 1) / BLK;      // 1563
    const int g_l1   = (N_NODES * 8 + BLK - 1) / BLK;     // 1563
    const int g_l1f  = (N_NODES * 16) / BLK;              // 3125 (fallback, 16-lane)
    const int g_l2   = (NE_COL + 511) / 512;              // 1563

    k_count<<<g_edge, BLK, 0, stream>>>(src, dst, rel, cnt2, rank);
    k_degA<<<NBLK_N, 256, 0, stream>>>(cnt2, deg, bsum);
    k_degB<<<1, 256, 0, stream>>>(bsum);
    k_degC<<<NBLK_N, 256, 0, stream>>>(deg, bsum, off);
    k_fill<<<g_edge, BLK, 0, stream>>>(src, dst, rel, cnt2, rank, off, recs);
    k_w2<<<R_TOT, 128, 0, stream>>>(comps2, bases2, w2p);

    if (materialize_w1) {
        k_w1<<<g_w1, BLK, 0, stream>>>(comps1, bases1, (unsigned*)w1);  // overwrites cnt2/rank (dead)
        k_l1_gather<<<g_l1, BLK, 0, stream>>>(off, recs, (const unsigned*)w1, bias1, h);
    } else {
        k_l1_gather_fly<<<g_l1f, BLK, 0, stream>>>(off, recs, comps1, bases1, bias1, h);
    }

    k_l2_gather<<<g_l2, 512, 0, stream>>>(off, recs, h, w2p, bias2, out);
}